// Round 6
// baseline (434.531 us; speedup 1.0000x reference)
//
#include <hip/hip_runtime.h>

typedef __attribute__((ext_vector_type(4))) float f32x4;
typedef __attribute__((ext_vector_type(8))) short bf16x8;

static __device__ __forceinline__ unsigned short f2bf(float f) {
  union { float f; unsigned int u; } v;
  v.f = f;
  unsigned int r = v.u + 0x7fffu + ((v.u >> 16) & 1u);  // RNE
  return (unsigned short)(r >> 16);
}
static __device__ __forceinline__ unsigned packbf(float a, float b) {
  return (unsigned)f2bf(a) | ((unsigned)f2bf(b) << 16);
}
static __device__ __forceinline__ void gload16(const void* g, void* l) {
  __builtin_amdgcn_global_load_lds(
      (const __attribute__((address_space(1))) unsigned int*)g,
      (__attribute__((address_space(3))) unsigned int*)l, 16, 0, 0);
}

// ---------------------------------------------------------------------------
// LSQ 4-bit fake-quant + pack to fragment-linear bf16.
// lane l holds wq[n][k], n = cf*16 + (l&15), k = ks*32 + (l>>4)*8 + j.
// w1 addr: ((cf*8 + ks)*64 + l)*8   (cf-major)
// w2 addr: ((ks*16 + cf)*64 + l)*8  (ks-major)
// ---------------------------------------------------------------------------
__global__ void lsq_pack(const float* __restrict__ w1, const float* __restrict__ a1,
                         const float* __restrict__ w2, const float* __restrict__ a2,
                         unsigned short* __restrict__ pq)
{
  int g = blockIdx.x * 256 + threadIdx.x;     // 0..16383
  int gg = g & 8191;
  const float* w = (g < 8192) ? w1 : w2;
  float alpha = (g < 8192) ? *a1 : *a2;
  unsigned short* dst = pq + ((g < 8192) ? 0 : 65536);
  int l  = gg & 63;
  int ks = (gg >> 6) & 7;
  int cf = gg >> 9;
  int n  = cf * 16 + (l & 15);
  int kb = ks * 32 + (l >> 4) * 8;
  const float* src = w + n * 256 + kb;
  unsigned short e[8];
  #pragma unroll
  for (int j = 0; j < 8; ++j) {
    float q = src[j] / alpha;
    q = fminf(fmaxf(q, -8.f), 7.f);
    q = rintf(q) * alpha;                     // round-half-even == jnp.round
    e[j] = f2bf(q);
  }
  uint4 o;
  o.x = e[0] | ((unsigned)e[1] << 16);
  o.y = e[2] | ((unsigned)e[3] << 16);
  o.z = e[4] | ((unsigned)e[5] << 16);
  o.w = e[6] | ((unsigned)e[7] << 16);
  int di = (g < 8192) ? ((cf * 8 + ks) * 64 + l) : ((ks * 16 + cf) * 64 + l);
  *(uint4*)(dst + di * 8) = o;
}

// ---------------------------------------------------------------------------
// Fused: out = sigmoid(relu(x@wq1^T + b1) @ wq2^T + b2)
// 512 thr (8 waves), wave-tile 16 rows, block-tile 128 rows, 1 block/CU.
// w1 (128KB) + biases LDS-resident once; w2 frags streamed per-use from
// L1/L2 (all waves read the same 16KB slice -> L1 hits); h through a
// wave-PRIVATE 1KB LDS slice (no sync); x next-tile prefetched into regs in
// two halves under compute. ZERO barriers after the prologue.
// Regs/wave ~ raw64 + xf32 + acc64 + w2dbuf32 + temps ~= 230 <= 256: no spill.
// LDS: 128K w1 + 1K b1 + 1K b2 + 8K h = 138.25 KB.
// ---------------------------------------------------------------------------
__global__ __launch_bounds__(512, 2) void lsq_fused(
    const float* __restrict__ x, const unsigned short* __restrict__ pqw,
    const float* __restrict__ b1, const float* __restrict__ b2,
    float* __restrict__ out, int ntiles)
{
  __shared__ __align__(16) char lds[131072 + 1024 + 1024 + 8192];
  char* const w1l = lds;
  char* const b1l = lds + 131072;
  char* const b2l = lds + 132096;

  const int tid  = threadIdx.x;
  const int lane = tid & 63;
  const int w    = tid >> 6;          // 0..7
  const int l15  = lane & 15;
  const int l4   = lane >> 4;
  char* const hl = lds + 133120 + w * 1024;   // wave-private h slice
  const int swz  = (l15 & 3) << 4;
  const char* pq1 = (const char*)pqw;
  const char* pq2 = (const char*)pqw + 131072;
  const int G = gridDim.x;
  const f32x4 fz = {0.f, 0.f, 0.f, 0.f};

  // ---- prologue: w1 (128KB) + biases -> LDS; first x tile -> regs ----
  #pragma unroll
  for (int it = 0; it < 16; ++it) {
    const int chunk = it * 8 + w;             // 0..127 x 1KB
    gload16(pq1 + chunk * 1024 + lane * 16, w1l + chunk * 1024);
  }
  if (w == 0) gload16((const char*)b1 + lane * 16, b1l);
  if (w == 1) gload16((const char*)b2 + lane * 16, b2l);

  int t = blockIdx.x;
  f32x4 raw[16];
  {
    const float* xp = x + ((size_t)t * 128 + w * 16 + l15) * 256;
    #pragma unroll
    for (int ks = 0; ks < 8; ++ks) {
      raw[2 * ks]     = *(const f32x4*)(xp + ks * 32 + l4 * 8);
      raw[2 * ks + 1] = *(const f32x4*)(xp + ks * 32 + l4 * 8 + 4);
    }
  }
  __syncthreads();   // the ONLY barrier: w1/bias LDS visible

  for (;;) {
    // convert raw -> bf16 B-frags (kills raw)
    bf16x8 xf[8];
    #pragma unroll
    for (int ks = 0; ks < 8; ++ks) {
      bf16x8 b;
      #pragma unroll
      for (int j = 0; j < 4; ++j) {
        b[j]     = (short)f2bf(raw[2 * ks][j]);
        b[j + 4] = (short)f2bf(raw[2 * ks + 1][j]);
      }
      xf[ks] = b;
    }

    const int tn = t + G;
    const bool more = tn < ntiles;
    const float* xq = x + ((size_t)tn * 128 + w * 16 + l15) * 256;

    f32x4 acc2[16];
    #pragma unroll
    for (int c2 = 0; c2 < 16; ++c2) acc2[c2] = fz;

    #pragma unroll
    for (int r = 0; r < 8; ++r) {
      // ---- layer-1: cf pair {2r, 2r+1} from LDS-resident w1 ----
      f32x4 a0 = fz, a1 = fz;
      #pragma unroll
      for (int ks = 0; ks < 8; ++ks) {
        bf16x8 wfA = *(const bf16x8*)(w1l + ((2 * r)     * 8 + ks) * 1024 + lane * 16);
        bf16x8 wfB = *(const bf16x8*)(w1l + ((2 * r + 1) * 8 + ks) * 1024 + lane * 16);
        a0 = __builtin_amdgcn_mfma_f32_16x16x32_bf16(wfA, xf[ks], a0, 0, 0, 0);
        a1 = __builtin_amdgcn_mfma_f32_16x16x32_bf16(wfB, xf[ks], a1, 0, 0, 0);
      }

      // cross-tile x prefetch, split halves under compute
      if (r == 2 && more) {
        #pragma unroll
        for (int ks = 0; ks < 4; ++ks) {
          raw[2 * ks]     = *(const f32x4*)(xq + ks * 32 + l4 * 8);
          raw[2 * ks + 1] = *(const f32x4*)(xq + ks * 32 + l4 * 8 + 4);
        }
      }
      if (r == 5 && more) {
        #pragma unroll
        for (int ks = 4; ks < 8; ++ks) {
          raw[2 * ks]     = *(const f32x4*)(xq + ks * 32 + l4 * 8);
          raw[2 * ks + 1] = *(const f32x4*)(xq + ks * 32 + l4 * 8 + 4);
        }
      }

      // ---- bias + relu + pack -> wave-private h LDS (C-layout) ----
      f32x4 bv0 = *(const f32x4*)(b1l + r * 128 + l4 * 16);
      f32x4 bv1 = *(const f32x4*)(b1l + r * 128 + 64 + l4 * 16);
      f32x4 v0, v1;
      #pragma unroll
      for (int j = 0; j < 4; ++j) {
        v0[j] = fmaxf(a0[j] + bv0[j], 0.f);
        v1[j] = fmaxf(a1[j] + bv1[j], 0.f);
      }
      {
        uint2 o0, o1;
        o0.x = packbf(v0[0], v0[1]);
        o0.y = packbf(v0[2], v0[3]);
        o1.x = packbf(v1[0], v1[1]);
        o1.y = packbf(v1[2], v1[3]);
        *(uint2*)(hl + l15 * 64 + ((l4 * 8) ^ swz))      = o0;
        *(uint2*)(hl + l15 * 64 + ((32 + l4 * 8) ^ swz)) = o1;
      }
      __builtin_amdgcn_sched_barrier(0);   // writes stay before the read
      bf16x8 hf = *(const bf16x8*)(hl + l15 * 64 + ((l4 * 16) ^ swz));

      // ---- layer-2 partial, ks2 = r; w2 streamed, rolling 4-frag dbuf ----
      bf16x8 wA[4], wB[4];
      #pragma unroll
      for (int i = 0; i < 4; ++i)
        wA[i] = *(const bf16x8*)(pq2 + (r * 16 + i) * 1024 + lane * 16);
      #pragma unroll
      for (int g2 = 0; g2 < 4; ++g2) {
        if (g2 < 3) {
          #pragma unroll
          for (int i = 0; i < 4; ++i) {
            bf16x8 v = *(const bf16x8*)(pq2 + (r * 16 + (g2 + 1) * 4 + i) * 1024 + lane * 16);
            if (g2 & 1) wA[i] = v; else wB[i] = v;
          }
        }
        __builtin_amdgcn_sched_barrier(0);  // cap held w2 frags at 8
        #pragma unroll
        for (int i = 0; i < 4; ++i) {
          bf16x8 cf = (g2 & 1) ? wB[i] : wA[i];
          acc2[g2 * 4 + i] =
              __builtin_amdgcn_mfma_f32_16x16x32_bf16(cf, hf, acc2[g2 * 4 + i], 0, 0, 0);
        }
      }
    }

    // ---- epilogue: bias2 + sigmoid + store ----
    {
      float* op = out + ((size_t)t * 128 + w * 16 + l15) * 256 + l4 * 4;
      #pragma unroll
      for (int c2 = 0; c2 < 16; ++c2) {
        f32x4 bb = *(const f32x4*)(b2l + c2 * 64 + l4 * 16);
        f32x4 o;
        #pragma unroll
        for (int j = 0; j < 4; ++j) {
          const float z = acc2[c2][j] + bb[j];
          o[j] = 1.f / (1.f + __expf(-z));
        }
        *(f32x4*)(op + c2 * 16) = o;
      }
    }
    if (!more) break;
    t = tn;
  }
}

// ---------------------------------------------------------------------------
extern "C" void kernel_launch(void* const* d_in, const int* in_sizes, int n_in,
                              void* d_out, int out_size, void* d_ws, size_t ws_size,
                              hipStream_t stream)
{
  const float* x  = (const float*)d_in[0];
  const float* w1 = (const float*)d_in[1];
  const float* b1 = (const float*)d_in[2];
  const float* a1 = (const float*)d_in[3];
  const float* w2 = (const float*)d_in[4];
  const float* b2 = (const float*)d_in[5];
  const float* a2 = (const float*)d_in[6];
  float* out = (float*)d_out;
  (void)ws_size;

  unsigned short* pq = (unsigned short*)d_ws;   // 256 KB packed weights

  long long totalRows = (long long)in_sizes[0] / 256;
  int ntiles = (int)(totalRows / 128);          // 2048 at N=262144

  lsq_pack<<<64, 256, 0, stream>>>(w1, a1, w2, a2, pq);

  int grid = ntiles < 256 ? ntiles : 256;       // 1 block/CU
  lsq_fused<<<grid, 512, 0, stream>>>(x, pq, b1, b2, out, ntiles);
}

// Round 7
// 323.185 us; speedup vs baseline: 1.3445x; 1.3445x over previous
//
#include <hip/hip_runtime.h>

typedef __attribute__((ext_vector_type(4))) float f32x4;
typedef __attribute__((ext_vector_type(8))) short bf16x8;
typedef __attribute__((ext_vector_type(4))) unsigned int u32x4;

static __device__ __forceinline__ unsigned short f2bf(float f) {
  union { float f; unsigned int u; } v;
  v.f = f;
  unsigned int r = v.u + 0x7fffu + ((v.u >> 16) & 1u);  // RNE
  return (unsigned short)(r >> 16);
}
static __device__ __forceinline__ unsigned packbf(float a, float b) {
  return (unsigned)f2bf(a) | ((unsigned)f2bf(b) << 16);
}
static __device__ __forceinline__ void gload16(const void* g, void* l) {
  __builtin_amdgcn_global_load_lds(
      (const __attribute__((address_space(1))) unsigned int*)g,
      (__attribute__((address_space(3))) unsigned int*)l, 16, 0, 0);
}

// ---------------------------------------------------------------------------
// LSQ 4-bit fake-quant + pack to fragment-linear bf16, cf-major for BOTH
// matrices: frag (cf, ks) at byte offset (cf*8 + ks)*1024; lane l holds
// wq[n][k], n = cf*16 + (l&15), k = ks*32 + (l>>4)*8 + j.
// Unified chunk space: chunk c in 0..15 at pq + c*16384 (c<8: w1, c>=8: w2).
// ---------------------------------------------------------------------------
__global__ void lsq_pack(const float* __restrict__ w1, const float* __restrict__ a1,
                         const float* __restrict__ w2, const float* __restrict__ a2,
                         unsigned short* __restrict__ pq)
{
  int g = blockIdx.x * 256 + threadIdx.x;     // 0..16383
  int gg = g & 8191;
  const float* w = (g < 8192) ? w1 : w2;
  float alpha = (g < 8192) ? *a1 : *a2;
  unsigned short* dst = pq + ((g < 8192) ? 0 : 65536);
  int l  = gg & 63;
  int ks = (gg >> 6) & 7;
  int cf = gg >> 9;
  int n  = cf * 16 + (l & 15);
  int kb = ks * 32 + (l >> 4) * 8;
  const float* src = w + n * 256 + kb;
  unsigned short e[8];
  #pragma unroll
  for (int j = 0; j < 8; ++j) {
    float q = src[j] / alpha;
    q = fminf(fmaxf(q, -8.f), 7.f);
    q = rintf(q) * alpha;                     // round-half-even == jnp.round
    e[j] = f2bf(q);
  }
  uint4 o;
  o.x = e[0] | ((unsigned)e[1] << 16);
  o.y = e[2] | ((unsigned)e[3] << 16);
  o.z = e[4] | ((unsigned)e[5] << 16);
  o.w = e[6] | ((unsigned)e[7] << 16);
  *(uint4*)(dst + ((cf * 8 + ks) * 64 + l) * 8) = o;
}

// ---------------------------------------------------------------------------
// Fused: out = sigmoid(relu(x@wq1^T + b1) @ wq2^T + b2)
// 256 thr (4 waves), wave-tile 16 rows, block-tile 64 rows.
// Per tile: 16 steps, one 16KB weight chunk each (2x16KB LDS dbuf, one
// __syncthreads per step). Steps 0..7: layer-1 cf-pair p -> hf[p] built
// IN-REGISTER via bpermute transpose (R3/R4-verified). Steps 8..15: layer-2
// c2-pair q from hf[0..7], acc transient (8 regs), store immediately.
// Next-tile x prefetched into regs at step 8 (xf dead there).
// LDS 34KB + <=170 regs/wave -> 3 blocks/CU: cross-block latency hiding.
// ---------------------------------------------------------------------------
__global__ __launch_bounds__(256, 3) void lsq_fused(
    const float* __restrict__ x, const unsigned short* __restrict__ pqw,
    const float* __restrict__ b1, const float* __restrict__ b2,
    float* __restrict__ out, int ntiles)
{
  __shared__ __align__(16) char wbuf[2][16384];
  __shared__ __align__(16) char b1l[1024];
  __shared__ __align__(16) char b2l[1024];

  const int tid  = threadIdx.x;
  const int lane = tid & 63;
  const int w    = tid >> 6;          // 0..3
  const int l15  = lane & 15;
  const int l4   = lane >> 4;
  const char* pq = (const char*)pqw;
  const int G = gridDim.x;
  const f32x4 fz = {0.f, 0.f, 0.f, 0.f};

  // bpermute gather indices (R3/R4-verified): byte addr = src_lane*4,
  // src lane = ((l4&1)*2 + (wi>>1))*16 + l15
  int idx[4];
  #pragma unroll
  for (int wi = 0; wi < 4; ++wi)
    idx[wi] = (((l4 & 1) * 2 + (wi >> 1)) * 16 + l15) * 4;

  // ---- prologue: chunk 0 + biases -> LDS; tile-0 x -> regs ----
  #pragma unroll
  for (int i = 0; i < 4; ++i) {
    const int sub = i * 4 + w;
    gload16(pq + sub * 1024 + lane * 16, &wbuf[0][0] + sub * 1024);
  }
  if (w == 0) gload16((const char*)b1 + lane * 16, b1l);
  if (w == 1) gload16((const char*)b2 + lane * 16, b2l);

  int t = blockIdx.x;
  f32x4 raw[16];
  if (t < ntiles) {
    const float* xp = x + ((size_t)t * 64 + w * 16 + l15) * 256 + l4 * 8;
    #pragma unroll
    for (int ks = 0; ks < 8; ++ks) {
      raw[2 * ks]     = *(const f32x4*)(xp + ks * 32);
      raw[2 * ks + 1] = *(const f32x4*)(xp + ks * 32 + 4);
    }
  }
  __syncthreads();

  for (; t < ntiles; ) {
    // ---- convert prefetched x -> bf16 B-frags (frees raw) ----
    bf16x8 xf[8];
    #pragma unroll
    for (int ks = 0; ks < 8; ++ks) {
      bf16x8 b;
      #pragma unroll
      for (int j = 0; j < 4; ++j) {
        b[j]     = (short)f2bf(raw[2 * ks][j]);
        b[j + 4] = (short)f2bf(raw[2 * ks + 1][j]);
      }
      xf[ks] = b;
    }

    const int tn = t + G;
    const bool more = tn < ntiles;
    const float* xq = x + ((size_t)tn * 64 + w * 16 + l15) * 256 + l4 * 8;

    bf16x8 hf[8];

    #pragma unroll
    for (int c = 0; c < 16; ++c) {
      // stage next chunk into the other buffer (its readers finished at the
      // barrier ending step c-1; this step's barrier drains the DMA)
      #pragma unroll
      for (int i = 0; i < 4; ++i) {
        const int sub = i * 4 + w;
        gload16(pq + ((c + 1) & 15) * 16384 + sub * 1024 + lane * 16,
                &wbuf[(c + 1) & 1][0] + sub * 1024);
      }
      if (c == 8 && more) {                  // x prefetch (xf is dead soon)
        #pragma unroll
        for (int ks = 0; ks < 8; ++ks) {
          raw[2 * ks]     = *(const f32x4*)(xq + ks * 32);
          raw[2 * ks + 1] = *(const f32x4*)(xq + ks * 32 + 4);
        }
      }
      const char* B = &wbuf[c & 1][0];

      if (c < 8) {
        // ---- layer-1 step p=c: cf pair {2p, 2p+1} -> hf[p] ----
        f32x4 a0 = fz, a1v = fz;
        #pragma unroll
        for (int ks = 0; ks < 8; ++ks) {
          bf16x8 wf0 = *(const bf16x8*)(B + ks * 1024 + lane * 16);
          bf16x8 wf1 = *(const bf16x8*)(B + 8192 + ks * 1024 + lane * 16);
          a0  = __builtin_amdgcn_mfma_f32_16x16x32_bf16(wf0, xf[ks], a0, 0, 0, 0);
          a1v = __builtin_amdgcn_mfma_f32_16x16x32_bf16(wf1, xf[ks], a1v, 0, 0, 0);
        }
        f32x4 bv0 = *(const f32x4*)(b1l + c * 128 + l4 * 16);
        f32x4 bv1 = *(const f32x4*)(b1l + c * 128 + 64 + l4 * 16);
        f32x4 v0, v1;
        #pragma unroll
        for (int j = 0; j < 4; ++j) {
          v0[j] = fmaxf(a0[j] + bv0[j], 0.f);
          v1[j] = fmaxf(a1v[j] + bv1[j], 0.f);
        }
        const unsigned D0 = packbf(v0[0], v0[1]);
        const unsigned D1 = packbf(v0[2], v0[3]);
        const unsigned D2 = packbf(v1[0], v1[1]);
        const unsigned D3 = packbf(v1[2], v1[3]);
        unsigned hd[4];
        #pragma unroll
        for (int wi = 0; wi < 4; ++wi) {
          const int p0 = __builtin_amdgcn_ds_bpermute(idx[wi], (int)((wi & 1) ? D1 : D0));
          const int p1 = __builtin_amdgcn_ds_bpermute(idx[wi], (int)((wi & 1) ? D3 : D2));
          hd[wi] = (l4 >= 2) ? (unsigned)p1 : (unsigned)p0;
        }
        union { u32x4 u; bf16x8 v; } cv;
        cv.u[0] = hd[0]; cv.u[1] = hd[1]; cv.u[2] = hd[2]; cv.u[3] = hd[3];
        hf[c] = cv.v;
      } else {
        // ---- layer-2 step q=c-8: c2 pair {2q, 2q+1}, store immediately ----
        const int q = c - 8;
        f32x4 g0 = fz, g1 = fz;
        #pragma unroll
        for (int ks2 = 0; ks2 < 8; ++ks2) {
          bf16x8 wf0 = *(const bf16x8*)(B + ks2 * 1024 + lane * 16);
          bf16x8 wf1 = *(const bf16x8*)(B + 8192 + ks2 * 1024 + lane * 16);
          g0 = __builtin_amdgcn_mfma_f32_16x16x32_bf16(wf0, hf[ks2], g0, 0, 0, 0);
          g1 = __builtin_amdgcn_mfma_f32_16x16x32_bf16(wf1, hf[ks2], g1, 0, 0, 0);
        }
        f32x4 bb0 = *(const f32x4*)(b2l + q * 128 + l4 * 16);
        f32x4 bb1 = *(const f32x4*)(b2l + q * 128 + 64 + l4 * 16);
        float* op = out + ((size_t)t * 64 + w * 16 + l15) * 256 + l4 * 4;
        f32x4 o0, o1;
        #pragma unroll
        for (int j = 0; j < 4; ++j) {
          const float z0 = g0[j] + bb0[j];
          const float z1 = g1[j] + bb1[j];
          o0[j] = 1.f / (1.f + __expf(-z0));
          o1[j] = 1.f / (1.f + __expf(-z1));
        }
        *(f32x4*)(op + (2 * q) * 16)     = o0;
        *(f32x4*)(op + (2 * q + 1) * 16) = o1;
      }
      __syncthreads();   // drains staging DMA (+x prefetch at c==8); retires readers
    }
    if (!more) break;
    t = tn;
  }
}

// ---------------------------------------------------------------------------
extern "C" void kernel_launch(void* const* d_in, const int* in_sizes, int n_in,
                              void* d_out, int out_size, void* d_ws, size_t ws_size,
                              hipStream_t stream)
{
  const float* x  = (const float*)d_in[0];
  const float* w1 = (const float*)d_in[1];
  const float* b1 = (const float*)d_in[2];
  const float* a1 = (const float*)d_in[3];
  const float* w2 = (const float*)d_in[4];
  const float* b2 = (const float*)d_in[5];
  const float* a2 = (const float*)d_in[6];
  float* out = (float*)d_out;
  (void)ws_size;

  unsigned short* pq = (unsigned short*)d_ws;   // 256 KB packed weights

  long long totalRows = (long long)in_sizes[0] / 256;
  int ntiles = (int)(totalRows / 64);           // 4096 at N=262144

  lsq_pack<<<64, 256, 0, stream>>>(w1, a1, w2, a2, pq);

  int grid = ntiles < 768 ? ntiles : 768;       // 3 blocks/CU residency
  lsq_fused<<<grid, 256, 0, stream>>>(x, pq, b1, b2, out, ntiles);
}

// Round 8
// 240.073 us; speedup vs baseline: 1.8100x; 1.3462x over previous
//
#include <hip/hip_runtime.h>

typedef __attribute__((ext_vector_type(4))) float f32x4;
typedef __attribute__((ext_vector_type(8))) short bf16x8;
typedef __attribute__((ext_vector_type(4))) unsigned int u32x4;

static __device__ __forceinline__ unsigned short f2bf(float f) {
  union { float f; unsigned int u; } v;
  v.f = f;
  unsigned int r = v.u + 0x7fffu + ((v.u >> 16) & 1u);  // RNE
  return (unsigned short)(r >> 16);
}
static __device__ __forceinline__ unsigned packbf(float a, float b) {
  return (unsigned)f2bf(a) | ((unsigned)f2bf(b) << 16);
}
static __device__ __forceinline__ void gload16(const void* g, void* l) {
  __builtin_amdgcn_global_load_lds(
      (const __attribute__((address_space(1))) unsigned int*)g,
      (__attribute__((address_space(3))) unsigned int*)l, 16, 0, 0);
}

// ---------------------------------------------------------------------------
// Pack LSQ 4-bit codes (k = round(clip(w/alpha,-8,7)), NOT scaled) as nibbles,
// fragment-linear. Word for (m, cf, ks, lane l) at index (m*128 + cf*8+ks)*64+l,
// nibble j = code for wq[n][k], n = cf*16 + (l&15), k = ks*32 + (l>>4)*8 + j.
// Both matrices = 64 KB total. Alpha is folded into the fused epilogue.
// ---------------------------------------------------------------------------
__global__ void lsq_pack_codes(const float* __restrict__ w1, const float* __restrict__ a1,
                               const float* __restrict__ w2, const float* __restrict__ a2,
                               unsigned* __restrict__ codes)
{
  int g = blockIdx.x * 256 + threadIdx.x;     // 0..16383
  int gg = g & 8191;
  const float* w = (g < 8192) ? w1 : w2;
  float alpha = (g < 8192) ? *a1 : *a2;
  int m  = g >> 13;                            // 0: w1, 1: w2
  int l  = gg & 63;
  int ks = (gg >> 6) & 7;
  int cf = gg >> 9;
  int n  = cf * 16 + (l & 15);
  int kb = ks * 32 + (l >> 4) * 8;
  const float* src = w + n * 256 + kb;
  unsigned cw = 0;
  #pragma unroll
  for (int j = 0; j < 8; ++j) {
    float q = src[j] / alpha;
    q = fminf(fmaxf(q, -8.f), 7.f);
    int k = (int)rintf(q);                     // round-half-even == jnp.round
    cw |= ((unsigned)k & 0xFu) << (4 * j);
  }
  codes[(m * 128 + cf * 8 + ks) * 64 + l] = cw;
}

// Dequant one frag: nibble codes -> bf16 integers (-8..7 exact; truncation
// of fp32 to top-16 bits is exact for these values).
static __device__ __forceinline__ bf16x8 deq(const char* cbase, int fr) {
  unsigned cw = *(const unsigned*)(cbase + (fr << 8));
  union { u32x4 u; bf16x8 v; } cv;
  #pragma unroll
  for (int p = 0; p < 4; ++p) {
    int k0 = ((int)(cw << (28 - 8 * p))) >> 28;
    int k1 = ((int)(cw << (24 - 8 * p))) >> 28;
    cv.u[p] = __builtin_amdgcn_perm(__float_as_uint((float)k1),
                                    __float_as_uint((float)k0), 0x07060302u);
  }
  return cv.v;
}

// ---------------------------------------------------------------------------
// Fused: out = sigmoid(alpha2*(h_codes) ...) with weights as LDS-resident
// 4-bit codes. 512 thr (8 waves), wave-tile 16 rows, block-tile 128, 1 blk/CU.
// ZERO barriers after prologue; per-wave vmcnt(0) once per tile.
// x: cols 0..127 via register prefetch (raw[8]); cols 128..255 via
// global_load_lds into wave-private 8KB buffer (XOR-swizzled source).
// LDS: 64K codes + 1K b1 + 1K b2 + 64K x = 130 KB.
// ---------------------------------------------------------------------------
__global__ __launch_bounds__(512, 2) void lsq_fused(
    const float* __restrict__ x, const unsigned* __restrict__ codes_g,
    const float* __restrict__ b1, const float* __restrict__ b2,
    const float* __restrict__ a1p, const float* __restrict__ a2p,
    float* __restrict__ out, int ntiles)
{
  __shared__ __align__(16) char lds[65536 + 1024 + 1024 + 65536];
  char* const cds  = lds;                     // 64 KB codes (both matrices)
  char* const b1l  = lds + 65536;
  char* const b2l  = lds + 66560;
  char* const xall = lds + 67584;             // 8 x 8KB wave-private x bufs

  const int tid  = threadIdx.x;
  const int lane = tid & 63;
  const int w    = tid >> 6;
  const int l15  = lane & 15;
  const int l4   = lane >> 4;
  char* const xw = xall + w * 8192;
  const int sw   = (l15 & 7) << 4;
  const char* const cbase = cds + (lane << 2);   // ds_read base; frag via imm offset
  const int G = gridDim.x;
  const f32x4 fz = {0.f, 0.f, 0.f, 0.f};

  const float alpha1 = *a1p;
  const float alpha2 = *a2p;

  // bpermute gather indices (R3..R7-verified transpose)
  int idx[4];
  #pragma unroll
  for (int wi = 0; wi < 4; ++wi)
    idx[wi] = (((l4 & 1) * 2 + (wi >> 1)) * 16 + l15) * 4;

  // ---- prologue: codes + biases -> LDS; first tile x -> regs + DMA ----
  #pragma unroll
  for (int it = 0; it < 8; ++it) {
    const int chunk = it * 8 + w;              // 64 x 1KB
    gload16((const char*)codes_g + chunk * 1024 + lane * 16, cds + chunk * 1024);
  }
  if (w == 0) gload16((const char*)b1 + lane * 16, b1l);
  if (w == 1) gload16((const char*)b2 + lane * 16, b2l);

  int t = blockIdx.x;
  f32x4 raw[8];
  {
    const float* xp = x + ((size_t)t * 128 + w * 16 + l15) * 256 + l4 * 8;
    #pragma unroll
    for (int ks = 0; ks < 4; ++ks) {
      raw[2 * ks]     = *(const f32x4*)(xp + ks * 32);
      raw[2 * ks + 1] = *(const f32x4*)(xp + ks * 32 + 4);
    }
    const char* xg = (const char*)x + ((size_t)t * 128 + w * 16) * 1024;
    #pragma unroll
    for (int q = 0; q < 8; ++q) {
      const int row = 2 * q + (lane >> 5);
      gload16(xg + row * 1024 + 512 + (((lane & 31) * 16) ^ ((row & 7) << 4)),
              xw + q * 1024);
    }
  }
  __syncthreads();   // the ONLY block barrier: codes/biases visible

  for (;;) {
    asm volatile("s_waitcnt vmcnt(0)" ::: "memory");   // own x-DMA + old stores
    __builtin_amdgcn_sched_barrier(0);

    // ---- convert x -> bf16 B-frags: regs (ks 0..3) + LDS (ks 4..7) ----
    bf16x8 xf[8];
    #pragma unroll
    for (int ks = 0; ks < 4; ++ks) {
      bf16x8 b;
      #pragma unroll
      for (int j = 0; j < 4; ++j) {
        b[j]     = (short)f2bf(raw[2 * ks][j]);
        b[j + 4] = (short)f2bf(raw[2 * ks + 1][j]);
      }
      xf[ks] = b;
    }
    {
      const char* base = xw + (l15 >> 1) * 1024 + (l15 & 1) * 512;
      #pragma unroll
      for (int ks = 4; ks < 8; ++ks) {
        f32x4 r0 = *(const f32x4*)(base + (((ks - 4) * 128 + l4 * 32) ^ sw));
        f32x4 r1 = *(const f32x4*)(base + (((ks - 4) * 128 + l4 * 32 + 16) ^ sw));
        bf16x8 b;
        #pragma unroll
        for (int j = 0; j < 4; ++j) {
          b[j]     = (short)f2bf(r0[j]);
          b[j + 4] = (short)f2bf(r1[j]);
        }
        xf[ks] = b;
      }
    }
    __builtin_amdgcn_sched_barrier(0);   // reads of xw stay above re-staging

    // ---- stage next tile (regs + DMA), then compute ----
    const int tn = t + G;
    const bool more = tn < ntiles;
    if (more) {
      const float* xp = x + ((size_t)tn * 128 + w * 16 + l15) * 256 + l4 * 8;
      #pragma unroll
      for (int ks = 0; ks < 4; ++ks) {
        raw[2 * ks]     = *(const f32x4*)(xp + ks * 32);
        raw[2 * ks + 1] = *(const f32x4*)(xp + ks * 32 + 4);
      }
      const char* xg = (const char*)x + ((size_t)tn * 128 + w * 16) * 1024;
      #pragma unroll
      for (int q = 0; q < 8; ++q) {
        const int row = 2 * q + (lane >> 5);
        gload16(xg + row * 1024 + 512 + (((lane & 31) * 16) ^ ((row & 7) << 4)),
                xw + q * 1024);
      }
    }
    __builtin_amdgcn_sched_barrier(0);   // staging issued before compute

    // ---- layer 1: h frags fully in-register (bpermute transpose) ----
    bf16x8 hf[8];
    #pragma unroll
    for (int p = 0; p < 8; ++p) {
      f32x4 a0 = fz, a1v = fz;
      #pragma unroll
      for (int ks = 0; ks < 8; ++ks) {
        a0  = __builtin_amdgcn_mfma_f32_16x16x32_bf16(deq(cbase, p * 16 + ks), xf[ks], a0, 0, 0, 0);
        a1v = __builtin_amdgcn_mfma_f32_16x16x32_bf16(deq(cbase, p * 16 + 8 + ks), xf[ks], a1v, 0, 0, 0);
      }
      f32x4 bv0 = *(const f32x4*)(b1l + p * 128 + l4 * 16);
      f32x4 bv1 = *(const f32x4*)(b1l + p * 128 + 64 + l4 * 16);
      f32x4 v0, v1;
      #pragma unroll
      for (int j = 0; j < 4; ++j) {
        v0[j] = fmaxf(fmaf(a0[j],  alpha1, bv0[j]), 0.f);
        v1[j] = fmaxf(fmaf(a1v[j], alpha1, bv1[j]), 0.f);
      }
      const unsigned D0 = packbf(v0[0], v0[1]);
      const unsigned D1 = packbf(v0[2], v0[3]);
      const unsigned D2 = packbf(v1[0], v1[1]);
      const unsigned D3 = packbf(v1[2], v1[3]);
      unsigned hd[4];
      #pragma unroll
      for (int wi = 0; wi < 4; ++wi) {
        const int p0 = __builtin_amdgcn_ds_bpermute(idx[wi], (int)((wi & 1) ? D1 : D0));
        const int p1 = __builtin_amdgcn_ds_bpermute(idx[wi], (int)((wi & 1) ? D3 : D2));
        hd[wi] = (l4 >= 2) ? (unsigned)p1 : (unsigned)p0;
      }
      union { u32x4 u; bf16x8 v; } cv;
      cv.u[0] = hd[0]; cv.u[1] = hd[1]; cv.u[2] = hd[2]; cv.u[3] = hd[3];
      hf[p] = cv.v;
    }

    // ---- layer 2: transient acc pairs, store immediately ----
    float* op = out + ((size_t)t * 128 + w * 16 + l15) * 256 + l4 * 4;
    #pragma unroll
    for (int q = 0; q < 8; ++q) {
      f32x4 g0 = fz, g1 = fz;
      #pragma unroll
      for (int ks2 = 0; ks2 < 8; ++ks2) {
        g0 = __builtin_amdgcn_mfma_f32_16x16x32_bf16(deq(cbase, 128 + q * 16 + ks2), hf[ks2], g0, 0, 0, 0);
        g1 = __builtin_amdgcn_mfma_f32_16x16x32_bf16(deq(cbase, 128 + q * 16 + 8 + ks2), hf[ks2], g1, 0, 0, 0);
      }
      f32x4 bb0 = *(const f32x4*)(b2l + q * 128 + l4 * 16);
      f32x4 bb1 = *(const f32x4*)(b2l + q * 128 + 64 + l4 * 16);
      f32x4 o0, o1;
      #pragma unroll
      for (int j = 0; j < 4; ++j) {
        const float z0 = fmaf(g0[j], alpha2, bb0[j]);
        const float z1 = fmaf(g1[j], alpha2, bb1[j]);
        o0[j] = 1.f / (1.f + __expf(-z0));
        o1[j] = 1.f / (1.f + __expf(-z1));
      }
      *(f32x4*)(op + (2 * q) * 16)     = o0;
      *(f32x4*)(op + (2 * q + 1) * 16) = o1;
    }

    if (!more) break;
    t = tn;
  }
}

// ---------------------------------------------------------------------------
extern "C" void kernel_launch(void* const* d_in, const int* in_sizes, int n_in,
                              void* d_out, int out_size, void* d_ws, size_t ws_size,
                              hipStream_t stream)
{
  const float* x  = (const float*)d_in[0];
  const float* w1 = (const float*)d_in[1];
  const float* b1 = (const float*)d_in[2];
  const float* a1 = (const float*)d_in[3];
  const float* w2 = (const float*)d_in[4];
  const float* b2 = (const float*)d_in[5];
  const float* a2 = (const float*)d_in[6];
  float* out = (float*)d_out;
  (void)ws_size;

  unsigned* codes = (unsigned*)d_ws;            // 64 KB nibble codes

  long long totalRows = (long long)in_sizes[0] / 256;
  int ntiles = (int)(totalRows / 128);          // 2048 at N=262144

  lsq_pack_codes<<<64, 256, 0, stream>>>(w1, a1, w2, a2, codes);

  int grid = ntiles < 256 ? ntiles : 256;       // 1 block/CU
  lsq_fused<<<grid, 512, 0, stream>>>(x, codes, b1, b2, a1, a2, out, ntiles);
}